// Round 1
// baseline (5840.506 us; speedup 1.0000x reference)
//
#include <hip/hip_runtime.h>

// GNetFVnewGCN: x[N,127], node_attr[N,1], edge_index[2,E] (int32), edge_attr[E,6],
// W_in[6,256], b_in[256], W_out[256,128], b_out[128] -> out[N,128] fp32
//
// Stage A: aggr (d_ws, N*256 fp32) zeroed via memset
// Stage B: edge kernel — wave/edge, scaling in regs, 4 atomicAdds/lane
// Stage C: node kernel — fp32 GEMM [N,256]@[256,128] + tanh, W_out in LDS (2 halves)

#define ATTR 6
#define NPB 32   // nodes per block in node kernel

__global__ __launch_bounds__(256) void edge_kernel(
    const float* __restrict__ x, const float* __restrict__ node_attr,
    const int* __restrict__ ei, const float* __restrict__ ea,
    const float* __restrict__ W_in, const float* __restrict__ b_in,
    float* __restrict__ aggr, int E, int N, int epw)
{
  const int lane = threadIdx.x & 63;
  const int wave = blockIdx.x * (blockDim.x >> 6) + (threadIdx.x >> 6);
  const int k0 = lane << 2;   // 4 contiguous k = c*2+h per lane
  const int c0 = lane << 1;   // 2 channels per lane

  // lin_in weights for this lane's 4 outputs, in registers (amortized over epw edges)
  float w[ATTR][4];
#pragma unroll
  for (int a = 0; a < ATTR; ++a) {
    const float4 t = *(const float4*)(W_in + a * 256 + k0);
    w[a][0] = t.x; w[a][1] = t.y; w[a][2] = t.z; w[a][3] = t.w;
  }
  const float4 bt = *(const float4*)(b_in + k0);

  const long e0 = (long)wave * epw;
  for (int i = 0; i < epw; ++i) {
    const long e = e0 + i;
    if (e >= E) return;
    const int src = ei[e];
    const int dst = ei[E + e];
    if ((unsigned)src >= (unsigned)N || (unsigned)dst >= (unsigned)N) continue;

    float eav[ATTR];
#pragma unroll
    for (int a = 0; a < ATTR; ++a) eav[a] = ea[(size_t)e * ATTR + a];

    float s0 = bt.x, s1 = bt.y, s2 = bt.z, s3 = bt.w;
#pragma unroll
    for (int a = 0; a < ATTR; ++a) {
      s0 = fmaf(eav[a], w[a][0], s0);
      s1 = fmaf(eav[a], w[a][1], s1);
      s2 = fmaf(eav[a], w[a][2], s2);
      s3 = fmaf(eav[a], w[a][3], s3);
    }
    s0 = fmaxf(s0, 0.f); s1 = fmaxf(s1, 0.f);
    s2 = fmaxf(s2, 0.f); s3 = fmaxf(s3, 0.f);

    // gather xc[src]: channels c0, c0+1 (c==127 comes from node_attr)
    const float* xr = x + (size_t)src * 127;
    const float x0 = xr[c0];
    const float x1 = (lane == 63) ? node_attr[src] : xr[c0 + 1];

    float* ap = aggr + (size_t)dst * 256 + k0;
    atomicAdd(ap + 0, s0 * x0);
    atomicAdd(ap + 1, s1 * x0);
    atomicAdd(ap + 2, s2 * x1);
    atomicAdd(ap + 3, s3 * x1);
  }
}

__global__ __launch_bounds__(256) void node_kernel(
    const float* __restrict__ aggr, const float* __restrict__ W_out,
    const float* __restrict__ b_out, float* __restrict__ out, int N)
{
  __shared__ float Wl[128 * 128];  // one k-half of W_out: 64 KB
  const int o = threadIdx.x & 127;
  const int g = threadIdx.x >> 7;  // node sub-group 0/1
  const int base = blockIdx.x * NPB;

  float acc[16];
#pragma unroll
  for (int j = 0; j < 16; ++j) acc[j] = 0.f;

  for (int half = 0; half < 2; ++half) {
    __syncthreads();
    const float4* srcv = (const float4*)(W_out + half * 128 * 128);
    float4* dstv = (float4*)Wl;
    for (int i = threadIdx.x; i < 128 * 128 / 4; i += 256) dstv[i] = srcv[i];
    __syncthreads();

    const int kbase = half * 128;
    for (int k = 0; k < 128; k += 4) {
      const float w0 = Wl[(k + 0) * 128 + o];
      const float w1 = Wl[(k + 1) * 128 + o];
      const float w2 = Wl[(k + 2) * 128 + o];
      const float w3 = Wl[(k + 3) * 128 + o];
#pragma unroll
      for (int j = 0; j < 16; ++j) {
        const int n = base + g + 2 * j;
        const float4 a4 = *(const float4*)(aggr + (size_t)n * 256 + kbase + k);
        acc[j] = fmaf(a4.x, w0, acc[j]);
        acc[j] = fmaf(a4.y, w1, acc[j]);
        acc[j] = fmaf(a4.z, w2, acc[j]);
        acc[j] = fmaf(a4.w, w3, acc[j]);
      }
    }
  }

  const float bo = b_out[o];
#pragma unroll
  for (int j = 0; j < 16; ++j) {
    const int n = base + g + 2 * j;
    if (n < N) out[(size_t)n * 128 + o] = tanhf(acc[j] + bo);
  }
}

extern "C" void kernel_launch(void* const* d_in, const int* in_sizes, int n_in,
                              void* d_out, int out_size, void* d_ws, size_t ws_size,
                              hipStream_t stream) {
  const float* x         = (const float*)d_in[0];
  const float* node_attr = (const float*)d_in[1];
  const int*   ei        = (const int*)d_in[2];
  const float* ea        = (const float*)d_in[3];
  const float* W_in      = (const float*)d_in[4];
  const float* b_in      = (const float*)d_in[5];
  const float* W_out     = (const float*)d_in[6];
  const float* b_out     = (const float*)d_in[7];
  float* out = (float*)d_out;

  const int N = in_sizes[0] / 127;   // 100000
  const int E = in_sizes[2] / 2;     // 1600000

  float* aggr = (float*)d_ws;        // [N, 256] fp32
  hipMemsetAsync(aggr, 0, (size_t)N * 256 * sizeof(float), stream);

  const int EPW = 4;                                   // edges per wave
  const int waves  = (E + EPW - 1) / EPW;
  const int eblocks = (waves + 3) / 4;                 // 4 waves per block
  edge_kernel<<<eblocks, 256, 0, stream>>>(x, node_attr, ei, ea, W_in, b_in,
                                           aggr, E, N, EPW);

  const int nblocks = (N + NPB - 1) / NPB;
  node_kernel<<<nblocks, 256, 0, stream>>>(aggr, W_out, b_out, out, N);
}

// Round 2
// 705.759 us; speedup vs baseline: 8.2755x; 8.2755x over previous
//
#include <hip/hip_runtime.h>

// GNetFVnewGCN: x[N,127], node_attr[N,1], edge_index[2,E] (int32), edge_attr[E,6],
// W_in[6,256], b_in[256], W_out[256,128], b_out[128] -> out[N,128] fp32
//
// R2: counting-sort edges by dst, then atomic-free per-node aggregation.
//   memset counts -> hist -> scan(3 kernels) -> scatter -> aggregate -> node GEMM
// Fallback to R1 atomic path if ws_size < ~110 MB.

#define ATTR 6
#define SCAN_CHUNK 1024

// ---------------- sort pipeline ----------------

__global__ __launch_bounds__(256) void hist_kernel(
    const int* __restrict__ ei, int* __restrict__ counts, int E)
{
  int e = blockIdx.x * 256 + threadIdx.x;
  if (e < E) atomicAdd(&counts[ei[E + e]], 1);
}

__global__ __launch_bounds__(256) void scan1_kernel(
    const int* __restrict__ counts, int* __restrict__ offsets,
    int* __restrict__ bsum, int N)
{
  __shared__ int sdata[256];
  const int t = threadIdx.x;
  const int base = blockIdx.x * SCAN_CHUNK + t * 4;
  int c[4]; int s = 0;
#pragma unroll
  for (int j = 0; j < 4; ++j) { int i = base + j; c[j] = (i < N) ? counts[i] : 0; s += c[j]; }
  sdata[t] = s;
  __syncthreads();
  for (int d = 1; d < 256; d <<= 1) {
    int tv = (t >= d) ? sdata[t - d] : 0;
    __syncthreads();
    sdata[t] += tv;
    __syncthreads();
  }
  int excl = sdata[t] - s;   // exclusive prefix of this thread within block
#pragma unroll
  for (int j = 0; j < 4; ++j) { int i = base + j; if (i < N) offsets[i] = excl; excl += c[j]; }
  if (t == 255) bsum[blockIdx.x] = sdata[255];
}

__global__ __launch_bounds__(256) void scan2_kernel(int* __restrict__ bsum, int nb)
{
  __shared__ int sdata[256];
  const int t = threadIdx.x;
  int v = (t < nb) ? bsum[t] : 0;
  int orig = v;
  sdata[t] = v;
  __syncthreads();
  for (int d = 1; d < 256; d <<= 1) {
    int tv = (t >= d) ? sdata[t - d] : 0;
    __syncthreads();
    sdata[t] += tv;
    __syncthreads();
  }
  if (t < nb) bsum[t] = sdata[t] - orig;   // exclusive
}

__global__ __launch_bounds__(256) void scan3_kernel(
    int* __restrict__ offsets, int* __restrict__ cursors,
    const int* __restrict__ bsum, int N, int E)
{
  const int base = blockIdx.x * SCAN_CHUNK + threadIdx.x * 4;
  const int add = bsum[blockIdx.x];
#pragma unroll
  for (int j = 0; j < 4; ++j) {
    int i = base + j;
    if (i < N) { int v = offsets[i] + add; offsets[i] = v; cursors[i] = v; }
  }
  if (blockIdx.x == 0 && threadIdx.x == 0) offsets[N] = E;
}

__global__ __launch_bounds__(256) void scatter_kernel(
    const int* __restrict__ ei, int* __restrict__ cursors,
    int* __restrict__ perm, int E)
{
  int e = blockIdx.x * 256 + threadIdx.x;
  if (e < E) {
    int dst = ei[E + e];
    int slot = atomicAdd(&cursors[dst], 1);
    perm[slot] = e;
  }
}

// ---------------- aggregation (atomic-free, wave per node) ----------------

__global__ __launch_bounds__(256) void aggregate_kernel(
    const float* __restrict__ x, const float* __restrict__ node_attr,
    const int* __restrict__ ei, const float* __restrict__ ea,
    const float* __restrict__ W_in, const float* __restrict__ b_in,
    const int* __restrict__ offsets, const int* __restrict__ perm,
    float* __restrict__ aggr, int N)
{
  const int lane = threadIdx.x & 63;
  const int n = blockIdx.x * 4 + (threadIdx.x >> 6);
  if (n >= N) return;
  const int k0 = lane << 2;   // 4 contiguous k = c*2+h per lane
  const int c0 = lane << 1;

  float w[ATTR][4];
#pragma unroll
  for (int a = 0; a < ATTR; ++a) {
    const float4 t = *(const float4*)(W_in + a * 256 + k0);
    w[a][0] = t.x; w[a][1] = t.y; w[a][2] = t.z; w[a][3] = t.w;
  }
  const float4 bt = *(const float4*)(b_in + k0);

  float a0 = 0.f, a1 = 0.f, a2 = 0.f, a3 = 0.f;
  const int beg = offsets[n], end = offsets[n + 1];

  int e = (beg < end) ? perm[beg] : 0;
  for (int i = beg; i < end; ++i) {
    const int src = ei[e];
    const int enext = (i + 1 < end) ? perm[i + 1] : 0;

    float eav[ATTR];
#pragma unroll
    for (int a = 0; a < ATTR; ++a) eav[a] = ea[(size_t)e * ATTR + a];

    float s0 = bt.x, s1 = bt.y, s2 = bt.z, s3 = bt.w;
#pragma unroll
    for (int a = 0; a < ATTR; ++a) {
      s0 = fmaf(eav[a], w[a][0], s0);
      s1 = fmaf(eav[a], w[a][1], s1);
      s2 = fmaf(eav[a], w[a][2], s2);
      s3 = fmaf(eav[a], w[a][3], s3);
    }
    s0 = fmaxf(s0, 0.f); s1 = fmaxf(s1, 0.f);
    s2 = fmaxf(s2, 0.f); s3 = fmaxf(s3, 0.f);

    const float* xr = x + (size_t)src * 127;
    const float x0 = xr[c0];
    const float x1 = (lane == 63) ? node_attr[src] : xr[c0 + 1];

    a0 = fmaf(s0, x0, a0); a1 = fmaf(s1, x0, a1);
    a2 = fmaf(s2, x1, a2); a3 = fmaf(s3, x1, a3);
    e = enext;
  }
  *(float4*)(aggr + (size_t)n * 256 + k0) = make_float4(a0, a1, a2, a3);
}

// ---------------- fallback atomic edge kernel (R1) ----------------

__global__ __launch_bounds__(256) void edge_kernel(
    const float* __restrict__ x, const float* __restrict__ node_attr,
    const int* __restrict__ ei, const float* __restrict__ ea,
    const float* __restrict__ W_in, const float* __restrict__ b_in,
    float* __restrict__ aggr, int E, int N, int epw)
{
  const int lane = threadIdx.x & 63;
  const int wave = blockIdx.x * (blockDim.x >> 6) + (threadIdx.x >> 6);
  const int k0 = lane << 2;
  const int c0 = lane << 1;

  float w[ATTR][4];
#pragma unroll
  for (int a = 0; a < ATTR; ++a) {
    const float4 t = *(const float4*)(W_in + a * 256 + k0);
    w[a][0] = t.x; w[a][1] = t.y; w[a][2] = t.z; w[a][3] = t.w;
  }
  const float4 bt = *(const float4*)(b_in + k0);

  const long e0 = (long)wave * epw;
  for (int i = 0; i < epw; ++i) {
    const long e = e0 + i;
    if (e >= E) return;
    const int src = ei[e];
    const int dst = ei[E + e];

    float eav[ATTR];
#pragma unroll
    for (int a = 0; a < ATTR; ++a) eav[a] = ea[(size_t)e * ATTR + a];

    float s0 = bt.x, s1 = bt.y, s2 = bt.z, s3 = bt.w;
#pragma unroll
    for (int a = 0; a < ATTR; ++a) {
      s0 = fmaf(eav[a], w[a][0], s0);
      s1 = fmaf(eav[a], w[a][1], s1);
      s2 = fmaf(eav[a], w[a][2], s2);
      s3 = fmaf(eav[a], w[a][3], s3);
    }
    s0 = fmaxf(s0, 0.f); s1 = fmaxf(s1, 0.f);
    s2 = fmaxf(s2, 0.f); s3 = fmaxf(s3, 0.f);

    const float* xr = x + (size_t)src * 127;
    const float x0 = xr[c0];
    const float x1 = (lane == 63) ? node_attr[src] : xr[c0 + 1];

    float* ap = aggr + (size_t)dst * 256 + k0;
    atomicAdd(ap + 0, s0 * x0);
    atomicAdd(ap + 1, s1 * x0);
    atomicAdd(ap + 2, s2 * x1);
    atomicAdd(ap + 3, s3 * x1);
  }
}

// ---------------- node GEMM + tanh (LDS-tiled, 64n x 128o per block) ----------------

__global__ __launch_bounds__(256) void node_kernel2(
    const float* __restrict__ aggr, const float* __restrict__ W_out,
    const float* __restrict__ b_out, float* __restrict__ out, int N)
{
  __shared__ float Wl[64 * 128];   // 32 KB: k-chunk of W_out
  __shared__ float Al[64][68];     // 17 KB: 64 nodes x 64 ks (+4 pad)
  const int t = threadIdx.x;
  const int o4 = (t & 31) * 4;     // 4 outputs
  const int ng = t >> 5;           // node group 0..7 -> nodes ng*8..ng*8+7
  const int nbase = blockIdx.x * 64;

  float acc[8][4];
#pragma unroll
  for (int j = 0; j < 8; ++j)
#pragma unroll
    for (int q = 0; q < 4; ++q) acc[j][q] = 0.f;

  for (int kc = 0; kc < 4; ++kc) {
    __syncthreads();
    // stage W chunk: rows [kc*64, kc*64+64) of W_out (contiguous 32 KB)
    const float4* wsrc = (const float4*)(W_out + kc * 64 * 128);
    float4* wdst = (float4*)Wl;
#pragma unroll
    for (int i = 0; i < 8; ++i) wdst[t + 256 * i] = wsrc[t + 256 * i];
    // stage A chunk: 64 rows x 64 ks
    {
      const int r = t >> 2, q = t & 3;
      int row = nbase + r; if (row >= N) row = N - 1;
      const float4* asrc = (const float4*)(aggr + (size_t)row * 256 + kc * 64 + q * 16);
      float4 v0 = asrc[0], v1 = asrc[1], v2 = asrc[2], v3 = asrc[3];
      float4* adst = (float4*)&Al[r][q * 16];
      adst[0] = v0; adst[1] = v1; adst[2] = v2; adst[3] = v3;
    }
    __syncthreads();

    for (int k = 0; k < 64; k += 4) {
      float4 a4[8];
#pragma unroll
      for (int j = 0; j < 8; ++j) a4[j] = *(const float4*)&Al[ng * 8 + j][k];
#pragma unroll
      for (int kk = 0; kk < 4; ++kk) {
        const float4 w4 = *(const float4*)&Wl[(k + kk) * 128 + o4];
#pragma unroll
        for (int j = 0; j < 8; ++j) {
          const float av = (&a4[j].x)[kk];
          acc[j][0] = fmaf(av, w4.x, acc[j][0]);
          acc[j][1] = fmaf(av, w4.y, acc[j][1]);
          acc[j][2] = fmaf(av, w4.z, acc[j][2]);
          acc[j][3] = fmaf(av, w4.w, acc[j][3]);
        }
      }
    }
  }

  const float4 b4 = *(const float4*)(b_out + o4);
#pragma unroll
  for (int j = 0; j < 8; ++j) {
    const int n = nbase + ng * 8 + j;
    if (n < N) {
      float4 r;
      r.x = tanhf(acc[j][0] + b4.x);
      r.y = tanhf(acc[j][1] + b4.y);
      r.z = tanhf(acc[j][2] + b4.z);
      r.w = tanhf(acc[j][3] + b4.w);
      *(float4*)(out + (size_t)n * 128 + o4) = r;
    }
  }
}

// ---------------- launch ----------------

extern "C" void kernel_launch(void* const* d_in, const int* in_sizes, int n_in,
                              void* d_out, int out_size, void* d_ws, size_t ws_size,
                              hipStream_t stream) {
  const float* x         = (const float*)d_in[0];
  const float* node_attr = (const float*)d_in[1];
  const int*   ei        = (const int*)d_in[2];
  const float* ea        = (const float*)d_in[3];
  const float* W_in      = (const float*)d_in[4];
  const float* b_in      = (const float*)d_in[5];
  const float* W_out     = (const float*)d_in[6];
  const float* b_out     = (const float*)d_in[7];
  float* out = (float*)d_out;

  const int N = in_sizes[0] / 127;   // 100000
  const int E = in_sizes[2] / 2;     // 1600000

  auto align16 = [](size_t v) { return (v + 15) & ~(size_t)15; };
  const size_t szCounts  = align16((size_t)N * 4);
  const size_t szOffsets = align16(((size_t)N + 1) * 4);
  const size_t szCursors = align16((size_t)N * 4);
  const size_t szBsum    = 1024;
  const size_t szPerm    = align16((size_t)E * 4);
  const size_t szAggr    = (size_t)N * 256 * 4;
  const size_t need = szCounts + szOffsets + szCursors + szBsum + szPerm + szAggr;

  const int nodeBlocks = (N + 63) / 64;

  if (ws_size >= need) {
    char* p = (char*)d_ws;
    int* counts  = (int*)p;                 p += szCounts;
    int* offsets = (int*)p;                 p += szOffsets;
    int* cursors = (int*)p;                 p += szCursors;
    int* bsum    = (int*)p;                 p += szBsum;
    int* perm    = (int*)p;                 p += szPerm;
    float* aggr  = (float*)p;

    hipMemsetAsync(counts, 0, (size_t)N * 4, stream);

    const int eb = (E + 255) / 256;
    const int nb = (N + SCAN_CHUNK - 1) / SCAN_CHUNK;   // 98 (<= 256)
    hist_kernel<<<eb, 256, 0, stream>>>(ei, counts, E);
    scan1_kernel<<<nb, 256, 0, stream>>>(counts, offsets, bsum, N);
    scan2_kernel<<<1, 256, 0, stream>>>(bsum, nb);
    scan3_kernel<<<nb, 256, 0, stream>>>(offsets, cursors, bsum, N, E);
    scatter_kernel<<<eb, 256, 0, stream>>>(ei, cursors, perm, E);
    aggregate_kernel<<<(N + 3) / 4, 256, 0, stream>>>(
        x, node_attr, ei, ea, W_in, b_in, offsets, perm, aggr, N);
    node_kernel2<<<nodeBlocks, 256, 0, stream>>>(aggr, W_out, b_out, out, N);
  } else {
    // fallback: atomic scatter path (needs only aggr in ws)
    float* aggr = (float*)d_ws;
    hipMemsetAsync(aggr, 0, (size_t)N * 256 * 4, stream);
    const int EPW = 4;
    const int waves = (E + EPW - 1) / EPW;
    edge_kernel<<<(waves + 3) / 4, 256, 0, stream>>>(
        x, node_attr, ei, ea, W_in, b_in, aggr, E, N, EPW);
    node_kernel2<<<nodeBlocks, 256, 0, stream>>>(aggr, W_out, b_out, out, N);
  }
}

// Round 3
// 609.277 us; speedup vs baseline: 9.5860x; 1.1584x over previous
//
#include <hip/hip_runtime.h>

// GNetFVnewGCN: x[N,127], node_attr[N,1], edge_index[2,E] (int32), edge_attr[E,6],
// W_in[6,256], b_in[256], W_out[256,128], b_out[128] -> out[N,128] fp32
//
// R3: counting-sort by dst + atomic-free aggregation, now latency-optimized:
//   - scatter also writes srcs[] (kills the perm->ei->x 3-deep chain)
//   - aggregate: 4-way edge unroll for MLP, stride-1 gather (lane->c={L,64+L})
//   - tiered ws fallback: A (srcs) -> B (no srcs) -> C (atomic path)

#define ATTR 6
#define SCAN_CHUNK 1024

// ---------------- sort pipeline ----------------

__global__ __launch_bounds__(256) void hist_kernel(
    const int* __restrict__ ei, int* __restrict__ counts, int E)
{
  int e = blockIdx.x * 256 + threadIdx.x;
  if (e < E) atomicAdd(&counts[ei[E + e]], 1);
}

__global__ __launch_bounds__(256) void scan1_kernel(
    const int* __restrict__ counts, int* __restrict__ offsets,
    int* __restrict__ bsum, int N)
{
  __shared__ int sdata[256];
  const int t = threadIdx.x;
  const int base = blockIdx.x * SCAN_CHUNK + t * 4;
  int c[4]; int s = 0;
#pragma unroll
  for (int j = 0; j < 4; ++j) { int i = base + j; c[j] = (i < N) ? counts[i] : 0; s += c[j]; }
  sdata[t] = s;
  __syncthreads();
  for (int d = 1; d < 256; d <<= 1) {
    int tv = (t >= d) ? sdata[t - d] : 0;
    __syncthreads();
    sdata[t] += tv;
    __syncthreads();
  }
  int excl = sdata[t] - s;
#pragma unroll
  for (int j = 0; j < 4; ++j) { int i = base + j; if (i < N) offsets[i] = excl; excl += c[j]; }
  if (t == 255) bsum[blockIdx.x] = sdata[255];
}

__global__ __launch_bounds__(256) void scan2_kernel(int* __restrict__ bsum, int nb)
{
  __shared__ int sdata[256];
  const int t = threadIdx.x;
  int v = (t < nb) ? bsum[t] : 0;
  int orig = v;
  sdata[t] = v;
  __syncthreads();
  for (int d = 1; d < 256; d <<= 1) {
    int tv = (t >= d) ? sdata[t - d] : 0;
    __syncthreads();
    sdata[t] += tv;
    __syncthreads();
  }
  if (t < nb) bsum[t] = sdata[t] - orig;
}

__global__ __launch_bounds__(256) void scan3_kernel(
    int* __restrict__ offsets, int* __restrict__ cursors,
    const int* __restrict__ bsum, int N, int E)
{
  const int base = blockIdx.x * SCAN_CHUNK + threadIdx.x * 4;
  const int add = bsum[blockIdx.x];
#pragma unroll
  for (int j = 0; j < 4; ++j) {
    int i = base + j;
    if (i < N) { int v = offsets[i] + add; offsets[i] = v; cursors[i] = v; }
  }
  if (blockIdx.x == 0 && threadIdx.x == 0) offsets[N] = E;
}

__global__ __launch_bounds__(256) void scatter_kernel(
    const int* __restrict__ ei, int* __restrict__ cursors,
    int* __restrict__ perm, int* __restrict__ srcs, int E, int write_srcs)
{
  int e = blockIdx.x * 256 + threadIdx.x;
  if (e < E) {
    int dst = ei[E + e];
    int slot = atomicAdd(&cursors[dst], 1);
    perm[slot] = e;
    if (write_srcs) srcs[slot] = ei[e];
  }
}

// ---------------- aggregation: wave/node, 4-way unrolled ----------------

template<bool USE_SRCS>
__global__ __launch_bounds__(256) void aggregate4_kernel(
    const float* __restrict__ x, const float* __restrict__ node_attr,
    const int* __restrict__ ei, const float* __restrict__ ea,
    const float* __restrict__ W_in, const float* __restrict__ b_in,
    const int* __restrict__ offsets, const int* __restrict__ perm,
    const int* __restrict__ srcs,
    float* __restrict__ aggr, int N)
{
  const int L = threadIdx.x & 63;
  const int n = __builtin_amdgcn_readfirstlane(blockIdx.x * 4 + (threadIdx.x >> 6));
  if (n >= N) return;

  // lane L owns channels c_lo=L (k=2L,2L+1) and c_hi=64+L (k=128+2L,129+2L)
  float2 wlo[ATTR], whi[ATTR];
#pragma unroll
  for (int a = 0; a < ATTR; ++a) {
    wlo[a] = *(const float2*)(W_in + a * 256 + 2 * L);
    whi[a] = *(const float2*)(W_in + a * 256 + 128 + 2 * L);
  }
  const float2 blo = *(const float2*)(b_in + 2 * L);
  const float2 bhi = *(const float2*)(b_in + 128 + 2 * L);

  float alo0 = 0.f, alo1 = 0.f, ahi0 = 0.f, ahi1 = 0.f;
  const int beg = offsets[n], end = offsets[n + 1];

  for (int i0 = beg; i0 < end; i0 += 4) {
    const int cnt = end - i0;          // wave-uniform, >= 1
    int e4[4], s4[4];
#pragma unroll
    for (int j = 0; j < 4; ++j) {
      const int idx = i0 + ((j < cnt) ? j : cnt - 1);   // clamped (dup tail)
      e4[j] = perm[idx];
      if (USE_SRCS) s4[j] = srcs[idx];
    }
    if (!USE_SRCS) {
#pragma unroll
      for (int j = 0; j < 4; ++j) s4[j] = ei[e4[j]];
    }

    float eav[4][ATTR];
#pragma unroll
    for (int j = 0; j < 4; ++j)
#pragma unroll
      for (int a = 0; a < ATTR; ++a) eav[j][a] = ea[(size_t)e4[j] * ATTR + a];

    float xlo[4], xhi[4];
#pragma unroll
    for (int j = 0; j < 4; ++j) {
      const float* xr = x + (size_t)s4[j] * 127;
      xlo[j] = xr[L];
      xhi[j] = (L == 63) ? node_attr[s4[j]] : xr[64 + L];
    }
#pragma unroll
    for (int j = 0; j < 4; ++j)
      if (j >= cnt) { xlo[j] = 0.f; xhi[j] = 0.f; }   // kill tail duplicates

#pragma unroll
    for (int j = 0; j < 4; ++j) {
      float sl0 = blo.x, sl1 = blo.y, sh0 = bhi.x, sh1 = bhi.y;
#pragma unroll
      for (int a = 0; a < ATTR; ++a) {
        sl0 = fmaf(eav[j][a], wlo[a].x, sl0);
        sl1 = fmaf(eav[j][a], wlo[a].y, sl1);
        sh0 = fmaf(eav[j][a], whi[a].x, sh0);
        sh1 = fmaf(eav[j][a], whi[a].y, sh1);
      }
      sl0 = fmaxf(sl0, 0.f); sl1 = fmaxf(sl1, 0.f);
      sh0 = fmaxf(sh0, 0.f); sh1 = fmaxf(sh1, 0.f);
      alo0 = fmaf(sl0, xlo[j], alo0);
      alo1 = fmaf(sl1, xlo[j], alo1);
      ahi0 = fmaf(sh0, xhi[j], ahi0);
      ahi1 = fmaf(sh1, xhi[j], ahi1);
    }
  }

  *(float2*)(aggr + (size_t)n * 256 + 2 * L)       = make_float2(alo0, alo1);
  *(float2*)(aggr + (size_t)n * 256 + 128 + 2 * L) = make_float2(ahi0, ahi1);
}

// ---------------- fallback atomic edge kernel (tier C) ----------------

__global__ __launch_bounds__(256) void edge_kernel(
    const float* __restrict__ x, const float* __restrict__ node_attr,
    const int* __restrict__ ei, const float* __restrict__ ea,
    const float* __restrict__ W_in, const float* __restrict__ b_in,
    float* __restrict__ aggr, int E, int N, int epw)
{
  const int lane = threadIdx.x & 63;
  const int wave = blockIdx.x * (blockDim.x >> 6) + (threadIdx.x >> 6);
  const int k0 = lane << 2;
  const int c0 = lane << 1;

  float w[ATTR][4];
#pragma unroll
  for (int a = 0; a < ATTR; ++a) {
    const float4 t = *(const float4*)(W_in + a * 256 + k0);
    w[a][0] = t.x; w[a][1] = t.y; w[a][2] = t.z; w[a][3] = t.w;
  }
  const float4 bt = *(const float4*)(b_in + k0);

  const long e0 = (long)wave * epw;
  for (int i = 0; i < epw; ++i) {
    const long e = e0 + i;
    if (e >= E) return;
    const int src = ei[e];
    const int dst = ei[E + e];

    float eav[ATTR];
#pragma unroll
    for (int a = 0; a < ATTR; ++a) eav[a] = ea[(size_t)e * ATTR + a];

    float s0 = bt.x, s1 = bt.y, s2 = bt.z, s3 = bt.w;
#pragma unroll
    for (int a = 0; a < ATTR; ++a) {
      s0 = fmaf(eav[a], w[a][0], s0);
      s1 = fmaf(eav[a], w[a][1], s1);
      s2 = fmaf(eav[a], w[a][2], s2);
      s3 = fmaf(eav[a], w[a][3], s3);
    }
    s0 = fmaxf(s0, 0.f); s1 = fmaxf(s1, 0.f);
    s2 = fmaxf(s2, 0.f); s3 = fmaxf(s3, 0.f);

    const float* xr = x + (size_t)src * 127;
    const float x0 = xr[c0];
    const float x1 = (lane == 63) ? node_attr[src] : xr[c0 + 1];

    float* ap = aggr + (size_t)dst * 256 + k0;
    atomicAdd(ap + 0, s0 * x0);
    atomicAdd(ap + 1, s1 * x0);
    atomicAdd(ap + 2, s2 * x1);
    atomicAdd(ap + 3, s3 * x1);
  }
}

// ---------------- node GEMM + tanh (LDS-tiled, 64n x 128o per block) ----------------

__global__ __launch_bounds__(256) void node_kernel2(
    const float* __restrict__ aggr, const float* __restrict__ W_out,
    const float* __restrict__ b_out, float* __restrict__ out, int N)
{
  __shared__ float Wl[64 * 128];   // 32 KB: k-chunk of W_out
  __shared__ float Al[64][68];     // 17 KB: 64 nodes x 64 ks (+4 pad)
  const int t = threadIdx.x;
  const int o4 = (t & 31) * 4;
  const int ng = t >> 5;
  const int nbase = blockIdx.x * 64;

  float acc[8][4];
#pragma unroll
  for (int j = 0; j < 8; ++j)
#pragma unroll
    for (int q = 0; q < 4; ++q) acc[j][q] = 0.f;

  for (int kc = 0; kc < 4; ++kc) {
    __syncthreads();
    const float4* wsrc = (const float4*)(W_out + kc * 64 * 128);
    float4* wdst = (float4*)Wl;
#pragma unroll
    for (int i = 0; i < 8; ++i) wdst[t + 256 * i] = wsrc[t + 256 * i];
    {
      const int r = t >> 2, q = t & 3;
      int row = nbase + r; if (row >= N) row = N - 1;
      const float4* asrc = (const float4*)(aggr + (size_t)row * 256 + kc * 64 + q * 16);
      float4 v0 = asrc[0], v1 = asrc[1], v2 = asrc[2], v3 = asrc[3];
      float4* adst = (float4*)&Al[r][q * 16];
      adst[0] = v0; adst[1] = v1; adst[2] = v2; adst[3] = v3;
    }
    __syncthreads();

    for (int k = 0; k < 64; k += 4) {
      float4 a4[8];
#pragma unroll
      for (int j = 0; j < 8; ++j) a4[j] = *(const float4*)&Al[ng * 8 + j][k];
#pragma unroll
      for (int kk = 0; kk < 4; ++kk) {
        const float4 w4 = *(const float4*)&Wl[(k + kk) * 128 + o4];
#pragma unroll
        for (int j = 0; j < 8; ++j) {
          const float av = (&a4[j].x)[kk];
          acc[j][0] = fmaf(av, w4.x, acc[j][0]);
          acc[j][1] = fmaf(av, w4.y, acc[j][1]);
          acc[j][2] = fmaf(av, w4.z, acc[j][2]);
          acc[j][3] = fmaf(av, w4.w, acc[j][3]);
        }
      }
    }
  }

  const float4 b4 = *(const float4*)(b_out + o4);
#pragma unroll
  for (int j = 0; j < 8; ++j) {
    const int n = nbase + ng * 8 + j;
    if (n < N) {
      float4 r;
      r.x = tanhf(acc[j][0] + b4.x);
      r.y = tanhf(acc[j][1] + b4.y);
      r.z = tanhf(acc[j][2] + b4.z);
      r.w = tanhf(acc[j][3] + b4.w);
      *(float4*)(out + (size_t)n * 128 + o4) = r;
    }
  }
}

// ---------------- launch ----------------

extern "C" void kernel_launch(void* const* d_in, const int* in_sizes, int n_in,
                              void* d_out, int out_size, void* d_ws, size_t ws_size,
                              hipStream_t stream) {
  const float* x         = (const float*)d_in[0];
  const float* node_attr = (const float*)d_in[1];
  const int*   ei        = (const int*)d_in[2];
  const float* ea        = (const float*)d_in[3];
  const float* W_in      = (const float*)d_in[4];
  const float* b_in      = (const float*)d_in[5];
  const float* W_out     = (const float*)d_in[6];
  const float* b_out     = (const float*)d_in[7];
  float* out = (float*)d_out;

  const int N = in_sizes[0] / 127;   // 100000
  const int E = in_sizes[2] / 2;     // 1600000

  auto align16 = [](size_t v) { return (v + 15) & ~(size_t)15; };
  const size_t szCounts  = align16((size_t)N * 4);
  const size_t szOffsets = align16(((size_t)N + 1) * 4);
  const size_t szCursors = align16((size_t)N * 4);
  const size_t szBsum    = 1024;
  const size_t szPerm    = align16((size_t)E * 4);
  const size_t szSrcs    = align16((size_t)E * 4);
  const size_t szAggr    = (size_t)N * 256 * 4;
  const size_t needB = szCounts + szOffsets + szCursors + szBsum + szPerm + szAggr;
  const size_t needA = needB + szSrcs;

  const int nodeBlocks = (N + 63) / 64;
  const int eb = (E + 255) / 256;
  const int nb = (N + SCAN_CHUNK - 1) / SCAN_CHUNK;   // 98 (<= 256)

  if (ws_size >= needB) {
    const bool useSrcs = (ws_size >= needA);
    char* p = (char*)d_ws;
    int* counts  = (int*)p;                 p += szCounts;
    int* offsets = (int*)p;                 p += szOffsets;
    int* cursors = (int*)p;                 p += szCursors;
    int* bsum    = (int*)p;                 p += szBsum;
    int* perm    = (int*)p;                 p += szPerm;
    int* srcs    = nullptr;
    if (useSrcs) { srcs = (int*)p;          p += szSrcs; }
    float* aggr  = (float*)p;

    hipMemsetAsync(counts, 0, (size_t)N * 4, stream);

    hist_kernel<<<eb, 256, 0, stream>>>(ei, counts, E);
    scan1_kernel<<<nb, 256, 0, stream>>>(counts, offsets, bsum, N);
    scan2_kernel<<<1, 256, 0, stream>>>(bsum, nb);
    scan3_kernel<<<nb, 256, 0, stream>>>(offsets, cursors, bsum, N, E);
    scatter_kernel<<<eb, 256, 0, stream>>>(ei, cursors, perm, srcs, E,
                                           useSrcs ? 1 : 0);
    if (useSrcs) {
      aggregate4_kernel<true><<<(N + 3) / 4, 256, 0, stream>>>(
          x, node_attr, ei, ea, W_in, b_in, offsets, perm, srcs, aggr, N);
    } else {
      aggregate4_kernel<false><<<(N + 3) / 4, 256, 0, stream>>>(
          x, node_attr, ei, ea, W_in, b_in, offsets, perm, nullptr, aggr, N);
    }
    node_kernel2<<<nodeBlocks, 256, 0, stream>>>(aggr, W_out, b_out, out, N);
  } else {
    // tier C: atomic scatter path (needs only aggr in ws)
    float* aggr = (float*)d_ws;
    hipMemsetAsync(aggr, 0, (size_t)N * 256 * 4, stream);
    const int EPW = 4;
    const int waves = (E + EPW - 1) / EPW;
    edge_kernel<<<(waves + 3) / 4, 256, 0, stream>>>(
        x, node_attr, ei, ea, W_in, b_in, aggr, E, N, EPW);
    node_kernel2<<<nodeBlocks, 256, 0, stream>>>(aggr, W_out, b_out, out, N);
  }
}

// Round 4
// 569.573 us; speedup vs baseline: 10.2542x; 1.0697x over previous
//
#include <hip/hip_runtime.h>

// GNetFVnewGCN: x[N,127], node_attr[N,1], edge_index[2,E] (int32), edge_attr[E,6],
// W_in[6,256], b_in[256], W_out[256,128], b_out[128] -> out[N,128] fp32
//
// R4: counting-sort by dst with PAYLOAD scatter (srcs + edge_attr in slot order),
//     pre-concatenated xc[N][128] (aligned gathers, no L==63 case),
//     8-edge-unrolled atomic-free aggregation.
// Tiers: A (payload, ~200MB ws) -> B (R3 perm path, ~117MB) -> C (atomic).

#define ATTR 6
#define SCAN_CHUNK 1024

// ---------------- xc = concat(x, node_attr), 512B-aligned rows ----------------

__global__ __launch_bounds__(256) void concat_kernel(
    const float* __restrict__ x, const float* __restrict__ na,
    float* __restrict__ xc, int N)
{
  const int gid = blockIdx.x * 256 + threadIdx.x;   // one thread per 4 elems
  const int row = gid >> 5;
  const int c4 = (gid & 31) * 4;
  if (row >= N) return;
  const float* xr = x + (size_t)row * 127;
  float4 v;
  v.x = xr[c4];
  v.y = xr[c4 + 1];
  v.z = xr[c4 + 2];
  v.w = (c4 == 124) ? na[row] : xr[c4 + 3];
  *(float4*)(xc + (size_t)row * 128 + c4) = v;
}

// ---------------- sort pipeline ----------------

__global__ __launch_bounds__(256) void hist_kernel(
    const int* __restrict__ ei, int* __restrict__ counts, int E)
{
  int e = blockIdx.x * 256 + threadIdx.x;
  if (e < E) atomicAdd(&counts[ei[E + e]], 1);
}

__global__ __launch_bounds__(256) void scan1_kernel(
    const int* __restrict__ counts, int* __restrict__ offsets,
    int* __restrict__ bsum, int N)
{
  __shared__ int sdata[256];
  const int t = threadIdx.x;
  const int base = blockIdx.x * SCAN_CHUNK + t * 4;
  int c[4]; int s = 0;
#pragma unroll
  for (int j = 0; j < 4; ++j) { int i = base + j; c[j] = (i < N) ? counts[i] : 0; s += c[j]; }
  sdata[t] = s;
  __syncthreads();
  for (int d = 1; d < 256; d <<= 1) {
    int tv = (t >= d) ? sdata[t - d] : 0;
    __syncthreads();
    sdata[t] += tv;
    __syncthreads();
  }
  int excl = sdata[t] - s;
#pragma unroll
  for (int j = 0; j < 4; ++j) { int i = base + j; if (i < N) offsets[i] = excl; excl += c[j]; }
  if (t == 255) bsum[blockIdx.x] = sdata[255];
}

__global__ __launch_bounds__(256) void scan2_kernel(int* __restrict__ bsum, int nb)
{
  __shared__ int sdata[256];
  const int t = threadIdx.x;
  int v = (t < nb) ? bsum[t] : 0;
  int orig = v;
  sdata[t] = v;
  __syncthreads();
  for (int d = 1; d < 256; d <<= 1) {
    int tv = (t >= d) ? sdata[t - d] : 0;
    __syncthreads();
    sdata[t] += tv;
    __syncthreads();
  }
  if (t < nb) bsum[t] = sdata[t] - orig;
}

__global__ __launch_bounds__(256) void scan3_kernel(
    int* __restrict__ offsets, int* __restrict__ cursors,
    const int* __restrict__ bsum, int N, int E)
{
  const int base = blockIdx.x * SCAN_CHUNK + threadIdx.x * 4;
  const int add = bsum[blockIdx.x];
#pragma unroll
  for (int j = 0; j < 4; ++j) {
    int i = base + j;
    if (i < N) { int v = offsets[i] + add; offsets[i] = v; cursors[i] = v; }
  }
  if (blockIdx.x == 0 && threadIdx.x == 0) offsets[N] = E;
}

// tier A: scatter payload (src id + 6 edge_attr floats) into slot order
__global__ __launch_bounds__(256) void scatter_payload_kernel(
    const int* __restrict__ ei, const float* __restrict__ ea,
    int* __restrict__ cursors,
    int* __restrict__ srcs, float* __restrict__ eas, int E)
{
  int e = blockIdx.x * 256 + threadIdx.x;
  if (e < E) {
    const int dst = ei[E + e];
    const int slot = atomicAdd(&cursors[dst], 1);
    srcs[slot] = ei[e];
    const float2 a0 = *(const float2*)(ea + (size_t)e * ATTR + 0);
    const float2 a1 = *(const float2*)(ea + (size_t)e * ATTR + 2);
    const float2 a2 = *(const float2*)(ea + (size_t)e * ATTR + 4);
    float* ep = eas + (size_t)slot * ATTR;
    *(float2*)(ep + 0) = a0;
    *(float2*)(ep + 2) = a1;
    *(float2*)(ep + 4) = a2;
  }
}

// tier B: scatter edge ids + srcs (R3 style)
__global__ __launch_bounds__(256) void scatter_kernel(
    const int* __restrict__ ei, int* __restrict__ cursors,
    int* __restrict__ perm, int* __restrict__ srcs, int E)
{
  int e = blockIdx.x * 256 + threadIdx.x;
  if (e < E) {
    int dst = ei[E + e];
    int slot = atomicAdd(&cursors[dst], 1);
    perm[slot] = e;
    srcs[slot] = ei[e];
  }
}

// ---------------- tier A aggregation: wave/node, 8-way unrolled, no indirection ----

__global__ __launch_bounds__(256) void aggregate8_kernel(
    const float* __restrict__ xc,
    const float* __restrict__ W_in, const float* __restrict__ b_in,
    const int* __restrict__ offsets, const int* __restrict__ srcs,
    const float* __restrict__ eas,
    float* __restrict__ aggr, int N)
{
  const int L = threadIdx.x & 63;
  const int n = __builtin_amdgcn_readfirstlane(blockIdx.x * 4 + (threadIdx.x >> 6));
  if (n >= N) return;

  // lane L owns channels c_lo=L (k=2L,2L+1) and c_hi=64+L (k=128+2L,129+2L)
  float2 wlo[ATTR], whi[ATTR];
#pragma unroll
  for (int a = 0; a < ATTR; ++a) {
    wlo[a] = *(const float2*)(W_in + a * 256 + 2 * L);
    whi[a] = *(const float2*)(W_in + a * 256 + 128 + 2 * L);
  }
  const float2 blo = *(const float2*)(b_in + 2 * L);
  const float2 bhi = *(const float2*)(b_in + 128 + 2 * L);

  float alo0 = 0.f, alo1 = 0.f, ahi0 = 0.f, ahi1 = 0.f;
  const int beg = offsets[n], end = offsets[n + 1];

  for (int i0 = beg; i0 < end; i0 += 8) {
    const int cnt = end - i0;          // wave-uniform, >= 1 inside loop
    int s8[8];
#pragma unroll
    for (int j = 0; j < 8; ++j) {
      const int idx = i0 + ((j < cnt) ? j : cnt - 1);   // clamped (dup tail)
      s8[j] = srcs[idx];
    }
    float eav[8][ATTR];
#pragma unroll
    for (int j = 0; j < 8; ++j) {
      const int idx = i0 + ((j < cnt) ? j : cnt - 1);
#pragma unroll
      for (int a = 0; a < ATTR; ++a) eav[j][a] = eas[(size_t)idx * ATTR + a];
    }

    float xlo[8], xhi[8];
#pragma unroll
    for (int j = 0; j < 8; ++j) {
      const float* xr = xc + (size_t)s8[j] * 128;
      xlo[j] = xr[L];
      xhi[j] = xr[64 + L];
    }
#pragma unroll
    for (int j = 0; j < 8; ++j)
      if (j >= cnt) { xlo[j] = 0.f; xhi[j] = 0.f; }   // kill tail duplicates

#pragma unroll
    for (int j = 0; j < 8; ++j) {
      float sl0 = blo.x, sl1 = blo.y, sh0 = bhi.x, sh1 = bhi.y;
#pragma unroll
      for (int a = 0; a < ATTR; ++a) {
        sl0 = fmaf(eav[j][a], wlo[a].x, sl0);
        sl1 = fmaf(eav[j][a], wlo[a].y, sl1);
        sh0 = fmaf(eav[j][a], whi[a].x, sh0);
        sh1 = fmaf(eav[j][a], whi[a].y, sh1);
      }
      sl0 = fmaxf(sl0, 0.f); sl1 = fmaxf(sl1, 0.f);
      sh0 = fmaxf(sh0, 0.f); sh1 = fmaxf(sh1, 0.f);
      alo0 = fmaf(sl0, xlo[j], alo0);
      alo1 = fmaf(sl1, xlo[j], alo1);
      ahi0 = fmaf(sh0, xhi[j], ahi0);
      ahi1 = fmaf(sh1, xhi[j], ahi1);
    }
  }

  *(float2*)(aggr + (size_t)n * 256 + 2 * L)       = make_float2(alo0, alo1);
  *(float2*)(aggr + (size_t)n * 256 + 128 + 2 * L) = make_float2(ahi0, ahi1);
}

// ---------------- tier B aggregation (R3, perm+srcs) ----------------

__global__ __launch_bounds__(256) void aggregate4_kernel(
    const float* __restrict__ x, const float* __restrict__ node_attr,
    const int* __restrict__ ei, const float* __restrict__ ea,
    const float* __restrict__ W_in, const float* __restrict__ b_in,
    const int* __restrict__ offsets, const int* __restrict__ perm,
    const int* __restrict__ srcs,
    float* __restrict__ aggr, int N)
{
  const int L = threadIdx.x & 63;
  const int n = __builtin_amdgcn_readfirstlane(blockIdx.x * 4 + (threadIdx.x >> 6));
  if (n >= N) return;

  float2 wlo[ATTR], whi[ATTR];
#pragma unroll
  for (int a = 0; a < ATTR; ++a) {
    wlo[a] = *(const float2*)(W_in + a * 256 + 2 * L);
    whi[a] = *(const float2*)(W_in + a * 256 + 128 + 2 * L);
  }
  const float2 blo = *(const float2*)(b_in + 2 * L);
  const float2 bhi = *(const float2*)(b_in + 128 + 2 * L);

  float alo0 = 0.f, alo1 = 0.f, ahi0 = 0.f, ahi1 = 0.f;
  const int beg = offsets[n], end = offsets[n + 1];

  for (int i0 = beg; i0 < end; i0 += 4) {
    const int cnt = end - i0;
    int e4[4], s4[4];
#pragma unroll
    for (int j = 0; j < 4; ++j) {
      const int idx = i0 + ((j < cnt) ? j : cnt - 1);
      e4[j] = perm[idx];
      s4[j] = srcs[idx];
    }

    float eav[4][ATTR];
#pragma unroll
    for (int j = 0; j < 4; ++j)
#pragma unroll
      for (int a = 0; a < ATTR; ++a) eav[j][a] = ea[(size_t)e4[j] * ATTR + a];

    float xlo[4], xhi[4];
#pragma unroll
    for (int j = 0; j < 4; ++j) {
      const float* xr = x + (size_t)s4[j] * 127;
      xlo[j] = xr[L];
      xhi[j] = (L == 63) ? node_attr[s4[j]] : xr[64 + L];
    }
#pragma unroll
    for (int j = 0; j < 4; ++j)
      if (j >= cnt) { xlo[j] = 0.f; xhi[j] = 0.f; }

#pragma unroll
    for (int j = 0; j < 4; ++j) {
      float sl0 = blo.x, sl1 = blo.y, sh0 = bhi.x, sh1 = bhi.y;
#pragma unroll
      for (int a = 0; a < ATTR; ++a) {
        sl0 = fmaf(eav[j][a], wlo[a].x, sl0);
        sl1 = fmaf(eav[j][a], wlo[a].y, sl1);
        sh0 = fmaf(eav[j][a], whi[a].x, sh0);
        sh1 = fmaf(eav[j][a], whi[a].y, sh1);
      }
      sl0 = fmaxf(sl0, 0.f); sl1 = fmaxf(sl1, 0.f);
      sh0 = fmaxf(sh0, 0.f); sh1 = fmaxf(sh1, 0.f);
      alo0 = fmaf(sl0, xlo[j], alo0);
      alo1 = fmaf(sl1, xlo[j], alo1);
      ahi0 = fmaf(sh0, xhi[j], ahi0);
      ahi1 = fmaf(sh1, xhi[j], ahi1);
    }
  }

  *(float2*)(aggr + (size_t)n * 256 + 2 * L)       = make_float2(alo0, alo1);
  *(float2*)(aggr + (size_t)n * 256 + 128 + 2 * L) = make_float2(ahi0, ahi1);
}

// ---------------- tier C: atomic edge kernel ----------------

__global__ __launch_bounds__(256) void edge_kernel(
    const float* __restrict__ x, const float* __restrict__ node_attr,
    const int* __restrict__ ei, const float* __restrict__ ea,
    const float* __restrict__ W_in, const float* __restrict__ b_in,
    float* __restrict__ aggr, int E, int N, int epw)
{
  const int lane = threadIdx.x & 63;
  const int wave = blockIdx.x * (blockDim.x >> 6) + (threadIdx.x >> 6);
  const int k0 = lane << 2;
  const int c0 = lane << 1;

  float w[ATTR][4];
#pragma unroll
  for (int a = 0; a < ATTR; ++a) {
    const float4 t = *(const float4*)(W_in + a * 256 + k0);
    w[a][0] = t.x; w[a][1] = t.y; w[a][2] = t.z; w[a][3] = t.w;
  }
  const float4 bt = *(const float4*)(b_in + k0);

  const long e0 = (long)wave * epw;
  for (int i = 0; i < epw; ++i) {
    const long e = e0 + i;
    if (e >= E) return;
    const int src = ei[e];
    const int dst = ei[E + e];

    float eav[ATTR];
#pragma unroll
    for (int a = 0; a < ATTR; ++a) eav[a] = ea[(size_t)e * ATTR + a];

    float s0 = bt.x, s1 = bt.y, s2 = bt.z, s3 = bt.w;
#pragma unroll
    for (int a = 0; a < ATTR; ++a) {
      s0 = fmaf(eav[a], w[a][0], s0);
      s1 = fmaf(eav[a], w[a][1], s1);
      s2 = fmaf(eav[a], w[a][2], s2);
      s3 = fmaf(eav[a], w[a][3], s3);
    }
    s0 = fmaxf(s0, 0.f); s1 = fmaxf(s1, 0.f);
    s2 = fmaxf(s2, 0.f); s3 = fmaxf(s3, 0.f);

    const float* xr = x + (size_t)src * 127;
    const float x0 = xr[c0];
    const float x1 = (lane == 63) ? node_attr[src] : xr[c0 + 1];

    float* ap = aggr + (size_t)dst * 256 + k0;
    atomicAdd(ap + 0, s0 * x0);
    atomicAdd(ap + 1, s1 * x0);
    atomicAdd(ap + 2, s2 * x1);
    atomicAdd(ap + 3, s3 * x1);
  }
}

// ---------------- node GEMM + tanh (LDS-tiled, 64n x 128o per block) ----------------

__global__ __launch_bounds__(256) void node_kernel2(
    const float* __restrict__ aggr, const float* __restrict__ W_out,
    const float* __restrict__ b_out, float* __restrict__ out, int N)
{
  __shared__ float Wl[64 * 128];   // 32 KB: k-chunk of W_out
  __shared__ float Al[64][68];     // 17 KB: 64 nodes x 64 ks (+4 pad)
  const int t = threadIdx.x;
  const int o4 = (t & 31) * 4;
  const int ng = t >> 5;
  const int nbase = blockIdx.x * 64;

  float acc[8][4];
#pragma unroll
  for (int j = 0; j < 8; ++j)
#pragma unroll
    for (int q = 0; q < 4; ++q) acc[j][q] = 0.f;

  for (int kc = 0; kc < 4; ++kc) {
    __syncthreads();
    const float4* wsrc = (const float4*)(W_out + kc * 64 * 128);
    float4* wdst = (float4*)Wl;
#pragma unroll
    for (int i = 0; i < 8; ++i) wdst[t + 256 * i] = wsrc[t + 256 * i];
    {
      const int r = t >> 2, q = t & 3;
      int row = nbase + r; if (row >= N) row = N - 1;
      const float4* asrc = (const float4*)(aggr + (size_t)row * 256 + kc * 64 + q * 16);
      float4 v0 = asrc[0], v1 = asrc[1], v2 = asrc[2], v3 = asrc[3];
      float4* adst = (float4*)&Al[r][q * 16];
      adst[0] = v0; adst[1] = v1; adst[2] = v2; adst[3] = v3;
    }
    __syncthreads();

    for (int k = 0; k < 64; k += 4) {
      float4 a4[8];
#pragma unroll
      for (int j = 0; j < 8; ++j) a4[j] = *(const float4*)&Al[ng * 8 + j][k];
#pragma unroll
      for (int kk = 0; kk < 4; ++kk) {
        const float4 w4 = *(const float4*)&Wl[(k + kk) * 128 + o4];
#pragma unroll
        for (int j = 0; j < 8; ++j) {
          const float av = (&a4[j].x)[kk];
          acc[j][0] = fmaf(av, w4.x, acc[j][0]);
          acc[j][1] = fmaf(av, w4.y, acc[j][1]);
          acc[j][2] = fmaf(av, w4.z, acc[j][2]);
          acc[j][3] = fmaf(av, w4.w, acc[j][3]);
        }
      }
    }
  }

  const float4 b4 = *(const float4*)(b_out + o4);
#pragma unroll
  for (int j = 0; j < 8; ++j) {
    const int n = nbase + ng * 8 + j;
    if (n < N) {
      float4 r;
      r.x = tanhf(acc[j][0] + b4.x);
      r.y = tanhf(acc[j][1] + b4.y);
      r.z = tanhf(acc[j][2] + b4.z);
      r.w = tanhf(acc[j][3] + b4.w);
      *(float4*)(out + (size_t)n * 128 + o4) = r;
    }
  }
}

// ---------------- launch ----------------

extern "C" void kernel_launch(void* const* d_in, const int* in_sizes, int n_in,
                              void* d_out, int out_size, void* d_ws, size_t ws_size,
                              hipStream_t stream) {
  const float* x         = (const float*)d_in[0];
  const float* node_attr = (const float*)d_in[1];
  const int*   ei        = (const int*)d_in[2];
  const float* ea        = (const float*)d_in[3];
  const float* W_in      = (const float*)d_in[4];
  const float* b_in      = (const float*)d_in[5];
  const float* W_out     = (const float*)d_in[6];
  const float* b_out     = (const float*)d_in[7];
  float* out = (float*)d_out;

  const int N = in_sizes[0] / 127;   // 100000
  const int E = in_sizes[2] / 2;     // 1600000

  auto align16 = [](size_t v) { return (v + 15) & ~(size_t)15; };
  const size_t szCounts  = align16((size_t)N * 4);
  const size_t szOffsets = align16(((size_t)N + 1) * 4);
  const size_t szCursors = align16((size_t)N * 4);
  const size_t szBsum    = 1024;
  const size_t szPerm    = align16((size_t)E * 4);
  const size_t szSrcs    = align16((size_t)E * 4);
  const size_t szEas     = align16((size_t)E * ATTR * 4);
  const size_t szXc      = align16((size_t)N * 128 * 4);
  const size_t szAggr    = (size_t)N * 256 * 4;

  const size_t needA = szCounts + szOffsets + szCursors + szBsum +
                       szSrcs + szEas + szXc + szAggr;            // ~200 MB
  const size_t needB = szCounts + szOffsets + szCursors + szBsum +
                       szPerm + szSrcs + szAggr;                  // ~117 MB

  const int nodeBlocks = (N + 63) / 64;
  const int eb = (E + 255) / 256;
  const int nb = (N + SCAN_CHUNK - 1) / SCAN_CHUNK;   // 98 (<= 256)

  if (ws_size >= needA) {
    char* p = (char*)d_ws;
    int* counts   = (int*)p;     p += szCounts;
    int* offsets  = (int*)p;     p += szOffsets;
    int* cursors  = (int*)p;     p += szCursors;
    int* bsum     = (int*)p;     p += szBsum;
    int* srcs     = (int*)p;     p += szSrcs;
    float* eas    = (float*)p;   p += szEas;
    float* xc     = (float*)p;   p += szXc;
    float* aggr   = (float*)p;

    hipMemsetAsync(counts, 0, (size_t)N * 4, stream);

    concat_kernel<<<(N * 32 + 255) / 256, 256, 0, stream>>>(x, node_attr, xc, N);
    hist_kernel<<<eb, 256, 0, stream>>>(ei, counts, E);
    scan1_kernel<<<nb, 256, 0, stream>>>(counts, offsets, bsum, N);
    scan2_kernel<<<1, 256, 0, stream>>>(bsum, nb);
    scan3_kernel<<<nb, 256, 0, stream>>>(offsets, cursors, bsum, N, E);
    scatter_payload_kernel<<<eb, 256, 0, stream>>>(ei, ea, cursors, srcs, eas, E);
    aggregate8_kernel<<<(N + 3) / 4, 256, 0, stream>>>(
        xc, W_in, b_in, offsets, srcs, eas, aggr, N);
    node_kernel2<<<nodeBlocks, 256, 0, stream>>>(aggr, W_out, b_out, out, N);
  } else if (ws_size >= needB) {
    char* p = (char*)d_ws;
    int* counts   = (int*)p;     p += szCounts;
    int* offsets  = (int*)p;     p += szOffsets;
    int* cursors  = (int*)p;     p += szCursors;
    int* bsum     = (int*)p;     p += szBsum;
    int* perm     = (int*)p;     p += szPerm;
    int* srcs     = (int*)p;     p += szSrcs;
    float* aggr   = (float*)p;

    hipMemsetAsync(counts, 0, (size_t)N * 4, stream);

    hist_kernel<<<eb, 256, 0, stream>>>(ei, counts, E);
    scan1_kernel<<<nb, 256, 0, stream>>>(counts, offsets, bsum, N);
    scan2_kernel<<<1, 256, 0, stream>>>(bsum, nb);
    scan3_kernel<<<nb, 256, 0, stream>>>(offsets, cursors, bsum, N, E);
    scatter_kernel<<<eb, 256, 0, stream>>>(ei, cursors, perm, srcs, E);
    aggregate4_kernel<<<(N + 3) / 4, 256, 0, stream>>>(
        x, node_attr, ei, ea, W_in, b_in, offsets, perm, srcs, aggr, N);
    node_kernel2<<<nodeBlocks, 256, 0, stream>>>(aggr, W_out, b_out, out, N);
  } else {
    float* aggr = (float*)d_ws;
    hipMemsetAsync(aggr, 0, (size_t)N * 256 * 4, stream);
    const int EPW = 4;
    const int waves = (E + EPW - 1) / EPW;
    edge_kernel<<<(waves + 3) / 4, 256, 0, stream>>>(
        x, node_attr, ei, ea, W_in, b_in, aggr, E, N, EPW);
    node_kernel2<<<nodeBlocks, 256, 0, stream>>>(aggr, W_out, b_out, out, N);
  }
}